// Round 2
// baseline (820.191 us; speedup 1.0000x reference)
//
#include <hip/hip_runtime.h>
#include <math.h>

#define BATCH 128
#define SEQ 512
#define DIN 16
#define HID 32
#define G4 128   // 4*HID
#define DH 64    // 2*HID (BiLSTM concat dim)

__device__ __forceinline__ float sigf(float x) {
    return 1.0f / (1.0f + exp2f(x * -1.44269504f));
}
__device__ __forceinline__ float tanh_fast(float x) {
    float e = exp2f(x * 2.88539008f);      // e^{2x}
    return 1.0f - 2.0f / (e + 1.0f);       // NaN-safe at +/-inf
}

// ---------------- Kernel 1: BiLSTM scan ----------------
// grid: (BATCH*2) WGs, one per (b, direction). block: 128 threads (one per gate output).
__global__ __launch_bounds__(128) void lstm_kernel(
    const float* __restrict__ x,
    const float* __restrict__ Wf, const float* __restrict__ Uf, const float* __restrict__ bf,
    const float* __restrict__ Wb, const float* __restrict__ Ub, const float* __restrict__ bb,
    float* __restrict__ hbuf)    // [B, T, 64]  (fwd -> [:,:,0:32], bwd -> [:,:,32:64])
{
    const int b = blockIdx.x >> 1;
    const int dir = blockIdx.x & 1;
    const int j = threadIdx.x;

    const float* W = dir ? Wb : Wf;
    const float* U = dir ? Ub : Uf;
    const float* bias = dir ? bb : bf;

    float wreg[DIN];
#pragma unroll
    for (int d = 0; d < DIN; ++d) wreg[d] = W[d * G4 + j];
    float ureg[HID];
#pragma unroll
    for (int k = 0; k < HID; ++k) ureg[k] = U[k * G4 + j];
    const float bj = bias[j];

    __shared__ __align__(16) float xs[SEQ * DIN];   // 32 KB: whole x[b]
    __shared__ __align__(16) float hs[HID];
    __shared__ float zs[G4];

    for (int idx = j; idx < SEQ * DIN; idx += 128)
        xs[idx] = x[(size_t)b * SEQ * DIN + idx];
    if (j < HID) hs[j] = 0.0f;
    float c = 0.0f;
    __syncthreads();

    for (int t = 0; t < SEQ; ++t) {
        const int tt = dir ? (SEQ - 1 - t) : t;
        const float4* x4 = (const float4*)&xs[tt * DIN];
        const float4* h4 = (const float4*)hs;
        float z0 = bj, z1 = 0.f, z2 = 0.f, z3 = 0.f;
#pragma unroll
        for (int q = 0; q < 4; ++q) {
            float4 v = x4[q];
            z0 = fmaf(v.x, wreg[4 * q + 0], z0);
            z1 = fmaf(v.y, wreg[4 * q + 1], z1);
            z2 = fmaf(v.z, wreg[4 * q + 2], z2);
            z3 = fmaf(v.w, wreg[4 * q + 3], z3);
        }
#pragma unroll
        for (int q = 0; q < 8; ++q) {
            float4 v = h4[q];
            z0 = fmaf(v.x, ureg[4 * q + 0], z0);
            z1 = fmaf(v.y, ureg[4 * q + 1], z1);
            z2 = fmaf(v.z, ureg[4 * q + 2], z2);
            z3 = fmaf(v.w, ureg[4 * q + 3], z3);
        }
        zs[j] = (z0 + z1) + (z2 + z3);
        __syncthreads();
        if (j < HID) {
            const float zi = zs[j], zf = zs[HID + j], zg = zs[2 * HID + j], zo = zs[3 * HID + j];
            c = sigf(zf) * c + sigf(zi) * tanh_fast(zg);
            const float hv = sigf(zo) * tanh_fast(c);
            hs[j] = hv;
            hbuf[((size_t)b * SEQ + tt) * DH + dir * HID + j] = hv;
        }
        __syncthreads();
    }
}

// ---------------- Kernel 2: self-attention ----------------
// grid: BATCH*16 WGs, one per (b, 32-row block). block: 256 threads.
#define ROWS 32
#define CHUNK 128
#define SP 516   // S row stride (pad vs 512)
#define HP 68    // hsL row stride (pad vs 64)
#define KP 132   // ksT row stride (pad vs 128)
#define QP 36    // qT row stride (pad vs 32)

__global__ __launch_bounds__(256) void attn_kernel(
    const float* __restrict__ h, float* __restrict__ attg)
{
    const int b  = blockIdx.x >> 4;
    const int rb = blockIdx.x & 15;
    const int tid = threadIdx.x;
    const int row0 = rb * ROWS;

    __shared__ __align__(16) float S[ROWS][SP];     // 66.0 KB  scores block
    __shared__ __align__(16) float hsL[CHUNK][HP];  // 34.8 KB  keys chunk, row-major
    __shared__ __align__(16) float ksT[DH][KP];     // 33.8 KB  keys chunk, transposed
    __shared__ __align__(16) float qT[DH][QP];      //  9.2 KB  q block, transposed
    __shared__ float invl[ROWS];

    const float* hb = h + (size_t)b * SEQ * DH;

    // stage qT[d][r] = h[b][row0+r][d]
    for (int n = tid; n < ROWS * DH; n += 256) {
        int r = n >> 6, d = n & 63;
        qT[d][r] = hb[(row0 + r) * DH + d];
    }
    __syncthreads();

    const int kg = tid & 31, rg = tid >> 5;   // scores map: 32 key-groups x 8 row-groups

    for (int c = 0; c < SEQ / CHUNK; ++c) {
        // stage keys chunk (coalesced global, conflict-free LDS)
        for (int n = tid; n < CHUNK * DH; n += 256) {
            int s = n >> 6, d = n & 63;
            hsL[s][d] = hb[(c * CHUNK + s) * DH + d];
        }
        __syncthreads();
        // transpose via LDS
        for (int n = tid; n < CHUNK * DH; n += 256) {
            int s = n >> 6, d = n & 63;
            ksT[d][s] = hsL[s][d];
        }
        __syncthreads();
        // scores: 32x128 subtile, 4x4 register tiles
        float acc[4][4] = {};
        for (int d = 0; d < DH; ++d) {
            float4 q4 = *(const float4*)&qT[d][rg * 4];
            float4 k4 = *(const float4*)&ksT[d][kg * 4];
            float qv[4] = {q4.x, q4.y, q4.z, q4.w};
            float kv[4] = {k4.x, k4.y, k4.z, k4.w};
#pragma unroll
            for (int i = 0; i < 4; ++i)
#pragma unroll
                for (int jj = 0; jj < 4; ++jj)
                    acc[i][jj] = fmaf(qv[i], kv[jj], acc[i][jj]);
        }
#pragma unroll
        for (int i = 0; i < 4; ++i)
            *(float4*)&S[rg * 4 + i][c * CHUNK + kg * 4] =
                make_float4(acc[i][0], acc[i][1], acc[i][2], acc[i][3]);
        __syncthreads();   // S written; hsL/ksT free for next chunk
    }

    // softmax per row: unnormalized p = exp(s - m) in place, invl = 1/sum
    {
        const int r = tid >> 3, part = tid & 7;   // 8 threads per row, same wave
        float m = -1e30f;
        for (int u = 0; u < 16; ++u) {
            float4 v = *(const float4*)&S[r][part * 4 + u * 32];
            m = fmaxf(m, fmaxf(fmaxf(v.x, v.y), fmaxf(v.z, v.w)));
        }
        m = fmaxf(m, __shfl_xor(m, 1));
        m = fmaxf(m, __shfl_xor(m, 2));
        m = fmaxf(m, __shfl_xor(m, 4));
        float l = 0.f;
        for (int u = 0; u < 16; ++u) {
            float4 v = *(float4*)&S[r][part * 4 + u * 32];
            v.x = expf(v.x - m); v.y = expf(v.y - m);
            v.z = expf(v.z - m); v.w = expf(v.w - m);
            l += (v.x + v.y) + (v.z + v.w);
            *(float4*)&S[r][part * 4 + u * 32] = v;
        }
        l += __shfl_xor(l, 1);
        l += __shfl_xor(l, 2);
        l += __shfl_xor(l, 4);
        if (part == 0) invl[r] = 1.0f / l;
    }
    __syncthreads();

    // att = (P @ K) * invl, accumulate over key chunks
    const int dg = tid & 15, rg2 = tid >> 4;  // 16 d-groups x 16 row-pairs
    const int r0 = rg2 * 2;
    float acc2[2][4] = {};
    for (int c = 0; c < SEQ / CHUNK; ++c) {
        __syncthreads();   // previous chunk fully consumed before restage
        for (int n = tid; n < CHUNK * DH; n += 256) {
            int s = n >> 6, d = n & 63;
            hsL[s][d] = hb[(c * CHUNK + s) * DH + d];
        }
        __syncthreads();
        for (int sq = 0; sq < CHUNK / 4; ++sq) {
            float4 pa4 = *(const float4*)&S[r0][c * CHUNK + sq * 4];
            float4 pb4 = *(const float4*)&S[r0 + 1][c * CHUNK + sq * 4];
            float pa[4] = {pa4.x, pa4.y, pa4.z, pa4.w};
            float pb[4] = {pb4.x, pb4.y, pb4.z, pb4.w};
#pragma unroll
            for (int u = 0; u < 4; ++u) {
                float4 kv = *(const float4*)&hsL[sq * 4 + u][dg * 4];
                acc2[0][0] = fmaf(pa[u], kv.x, acc2[0][0]);
                acc2[0][1] = fmaf(pa[u], kv.y, acc2[0][1]);
                acc2[0][2] = fmaf(pa[u], kv.z, acc2[0][2]);
                acc2[0][3] = fmaf(pa[u], kv.w, acc2[0][3]);
                acc2[1][0] = fmaf(pb[u], kv.x, acc2[1][0]);
                acc2[1][1] = fmaf(pb[u], kv.y, acc2[1][1]);
                acc2[1][2] = fmaf(pb[u], kv.z, acc2[1][2]);
                acc2[1][3] = fmaf(pb[u], kv.w, acc2[1][3]);
            }
        }
    }
    const float il0 = invl[r0], il1 = invl[r0 + 1];
    float* outp0 = attg + ((size_t)b * SEQ + row0 + r0) * DH + dg * 4;
    float* outp1 = outp0 + DH;
    *(float4*)outp0 = make_float4(acc2[0][0] * il0, acc2[0][1] * il0,
                                  acc2[0][2] * il0, acc2[0][3] * il0);
    *(float4*)outp1 = make_float4(acc2[1][0] * il1, acc2[1][1] * il1,
                                  acc2[1][2] * il1, acc2[1][3] * il1);
}

// ---------------- Kernel 3: pooled + LSTM2 + dense ----------------
// grid: BATCH WGs. block: 128 threads.
__global__ __launch_bounds__(128) void final_kernel(
    const float* __restrict__ hbuf, const float* __restrict__ attg,
    const float* __restrict__ W2, const float* __restrict__ b2,
    const float* __restrict__ Wd1, const float* __restrict__ bd1,
    const float* __restrict__ Wd2, const float* __restrict__ bd2,
    float* __restrict__ out)
{
    const int b = blockIdx.x;
    const int tid = threadIdx.x;
    __shared__ float part[2][DH];
    __shared__ float pooled[DH];
    __shared__ float zsh[G4];
    __shared__ float h2[HID];
    __shared__ float a1[16];

    const float* hb = hbuf + (size_t)b * SEQ * DH;
    const float* ab = attg + (size_t)b * SEQ * DH;
    const int d = tid & 63, half = tid >> 6;
    float acc = 0.f;
    for (int t = half * (SEQ / 2); t < (half + 1) * (SEQ / 2); ++t)
        acc = fmaf(hb[t * DH + d], ab[t * DH + d], acc);
    part[half][d] = acc;
    __syncthreads();
    if (tid < DH) pooled[tid] = part[0][tid] + part[1][tid];
    __syncthreads();

    // z = pooled @ W2 + b2   (c0=0 so U2 term vanishes)
    float z = b2[tid];
    for (int k = 0; k < DH; ++k) z = fmaf(pooled[k], W2[k * G4 + tid], z);
    zsh[tid] = z;
    __syncthreads();
    if (tid < HID) {
        const float zi = zsh[tid], zg = zsh[2 * HID + tid], zo = zsh[3 * HID + tid];
        const float cc = sigf(zi) * tanh_fast(zg);
        h2[tid] = sigf(zo) * tanh_fast(cc);
    }
    __syncthreads();
    if (tid < 16) {
        float a = bd1[tid];
        for (int k = 0; k < HID; ++k) a = fmaf(h2[k], Wd1[k * 16 + tid], a);
        a1[tid] = fmaxf(a, 0.0f);
    }
    __syncthreads();
    if (tid == 0) {
        float y = bd2[0];
        for (int k = 0; k < 16; ++k) y = fmaf(a1[k], Wd2[k], y);
        out[b] = y;
    }
}

extern "C" void kernel_launch(void* const* d_in, const int* in_sizes, int n_in,
                              void* d_out, int out_size, void* d_ws, size_t ws_size,
                              hipStream_t stream)
{
    (void)in_sizes; (void)n_in; (void)out_size; (void)ws_size;
    const float* x   = (const float*)d_in[0];
    const float* Wf  = (const float*)d_in[1];
    const float* Uf  = (const float*)d_in[2];
    const float* bf  = (const float*)d_in[3];
    const float* Wb  = (const float*)d_in[4];
    const float* Ub  = (const float*)d_in[5];
    const float* bb  = (const float*)d_in[6];
    const float* W2  = (const float*)d_in[7];
    // d_in[8] = U2 is mathematically unused (zero initial state in second LSTM)
    const float* b2  = (const float*)d_in[9];
    const float* Wd1 = (const float*)d_in[10];
    const float* bd1 = (const float*)d_in[11];
    const float* Wd2 = (const float*)d_in[12];
    const float* bd2 = (const float*)d_in[13];
    float* out = (float*)d_out;

    float* hbuf = (float*)d_ws;                              // [B,T,64] 16.78 MB
    float* attg = hbuf + (size_t)BATCH * SEQ * DH;           // [B,T,64] 16.78 MB

    hipLaunchKernelGGL(lstm_kernel, dim3(BATCH * 2), dim3(128), 0, stream,
                       x, Wf, Uf, bf, Wb, Ub, bb, hbuf);
    hipLaunchKernelGGL(attn_kernel, dim3(BATCH * 16), dim3(256), 0, stream,
                       hbuf, attg);
    hipLaunchKernelGGL(final_kernel, dim3(BATCH), dim3(128), 0, stream,
                       hbuf, attg, W2, b2, Wd1, bd1, Wd2, bd2, out);
}

// Round 3
// 535.300 us; speedup vs baseline: 1.5322x; 1.5322x over previous
//
#include <hip/hip_runtime.h>
#include <math.h>

#define BATCH 128
#define SEQ 512
#define DIN 16
#define HID 32
#define G4 128   // 4*HID
#define DH 64    // 2*HID

__device__ __forceinline__ float sigf(float x) {
    return 1.0f / (1.0f + exp2f(x * -1.44269504f));
}
__device__ __forceinline__ float tanh_fast(float x) {
    float e = exp2f(x * 2.88539008f);      // e^{2x}
    return 1.0f - 2.0f / (e + 1.0f);       // NaN-safe at +/-inf
}
__device__ __forceinline__ float rlane(float v, int lane) {
    return __int_as_float(__builtin_amdgcn_readlane(__float_as_int(v), lane));
}

// ---------------- Kernel 1: BiLSTM scan, single wave per (b,dir), no barriers ----
// grid: BATCH*2 WGs x 64 threads. Thread t owns gate columns t and t+64.
// Lanes 0..31 hold (i_j, g_j), lanes 32..63 hold (f_j, o_j); h lives on lanes 0..31
// and is broadcast via v_readlane. f,o cross to low lanes via shfl_xor(32).
__global__ __launch_bounds__(64) void lstm_kernel(
    const float* __restrict__ x,
    const float* __restrict__ Wf, const float* __restrict__ Uf, const float* __restrict__ bf,
    const float* __restrict__ Wb, const float* __restrict__ Ub, const float* __restrict__ bb,
    float* __restrict__ hbuf)    // [B, T, 64] (fwd -> [:,:,0:32], bwd -> [:,:,32:64])
{
    const int b = blockIdx.x >> 1;
    const int dir = blockIdx.x & 1;
    const int t0 = threadIdx.x;

    const float* W = dir ? Wb : Wf;
    const float* U = dir ? Ub : Uf;
    const float* bias = dir ? bb : bf;
    const int c0 = t0, c1 = t0 + 64;

    float w0[DIN], w1[DIN];
#pragma unroll
    for (int d = 0; d < DIN; ++d) { w0[d] = W[d * G4 + c0]; w1[d] = W[d * G4 + c1]; }
    float u0[HID], u1[HID];
#pragma unroll
    for (int k = 0; k < HID; ++k) { u0[k] = U[k * G4 + c0]; u1[k] = U[k * G4 + c1]; }
    const float b0 = bias[c0], b1 = bias[c1];

    __shared__ __align__(16) float4 xs4[SEQ * 4];   // 32 KB: whole x[b] as float4s
    const float4* xg = (const float4*)(x + (size_t)b * SEQ * DIN);
    for (int i = t0; i < SEQ * 4; i += 64) xs4[i] = xg[i];
    __syncthreads();

    float c = 0.f, hv = 0.f;
    const bool lo = (t0 < 32);
    float* outp = hbuf + (size_t)b * SEQ * DH + dir * HID + (t0 & 31);

    int tt = dir ? (SEQ - 1) : 0;
    float4 xa = xs4[tt * 4 + 0], xb = xs4[tt * 4 + 1];
    float4 xc = xs4[tt * 4 + 2], xd = xs4[tt * 4 + 3];

    for (int t = 0; t < SEQ; ++t) {
        const int tcur = tt;
        // software-prefetch next step's x (broadcast LDS reads, latency hidden by U-part)
        const int tn1 = t + 1 < SEQ ? t + 1 : SEQ - 1;
        const int tnx = dir ? (SEQ - 1 - tn1) : tn1;
        float4 na = xs4[tnx * 4 + 0], nb = xs4[tnx * 4 + 1];
        float4 nc = xs4[tnx * 4 + 2], nd = xs4[tnx * 4 + 3];

        // z = b + x_t . W  (2 accumulators per column)
        float p00 = b0, p01 = 0.f, p10 = b1, p11 = 0.f;
        p00 = fmaf(xa.x, w0[0], p00);  p00 = fmaf(xa.y, w0[1], p00);
        p00 = fmaf(xa.z, w0[2], p00);  p00 = fmaf(xa.w, w0[3], p00);
        p00 = fmaf(xb.x, w0[4], p00);  p00 = fmaf(xb.y, w0[5], p00);
        p00 = fmaf(xb.z, w0[6], p00);  p00 = fmaf(xb.w, w0[7], p00);
        p01 = fmaf(xc.x, w0[8], p01);  p01 = fmaf(xc.y, w0[9], p01);
        p01 = fmaf(xc.z, w0[10], p01); p01 = fmaf(xc.w, w0[11], p01);
        p01 = fmaf(xd.x, w0[12], p01); p01 = fmaf(xd.y, w0[13], p01);
        p01 = fmaf(xd.z, w0[14], p01); p01 = fmaf(xd.w, w0[15], p01);
        p10 = fmaf(xa.x, w1[0], p10);  p10 = fmaf(xa.y, w1[1], p10);
        p10 = fmaf(xa.z, w1[2], p10);  p10 = fmaf(xa.w, w1[3], p10);
        p10 = fmaf(xb.x, w1[4], p10);  p10 = fmaf(xb.y, w1[5], p10);
        p10 = fmaf(xb.z, w1[6], p10);  p10 = fmaf(xb.w, w1[7], p10);
        p11 = fmaf(xc.x, w1[8], p11);  p11 = fmaf(xc.y, w1[9], p11);
        p11 = fmaf(xc.z, w1[10], p11); p11 = fmaf(xc.w, w1[11], p11);
        p11 = fmaf(xd.x, w1[12], p11); p11 = fmaf(xd.y, w1[13], p11);
        p11 = fmaf(xd.z, w1[14], p11); p11 = fmaf(xd.w, w1[15], p11);

        // z += h . U  (h broadcast from lanes 0..31 via readlane)
#pragma unroll
        for (int k = 0; k < HID; k += 2) {
            float h0 = rlane(hv, k);
            float h1 = rlane(hv, k + 1);
            p00 = fmaf(h0, u0[k], p00);
            p10 = fmaf(h0, u1[k], p10);
            p01 = fmaf(h1, u0[k + 1], p01);
            p11 = fmaf(h1, u1[k + 1], p11);
        }
        const float z0 = p00 + p01, z1 = p10 + p11;

        // lanes<32: z0=zi, z1=zg ; lanes>=32: z0=zf, z1=zo
        const float g0 = sigf(z0);                         // si | sf
        const float g1 = lo ? tanh_fast(z1) : sigf(z1);    // tg | so
        const float fo0 = __shfl_xor(g0, 32);              // sf (on low lanes)
        const float fo1 = __shfl_xor(g1, 32);              // so (on low lanes)
        c = fmaf(fo0, c, g0 * g1);                         // c = sf*c + si*tg
        hv = fo1 * tanh_fast(c);                           // h = so*tanh(c)
        if (lo) outp[(size_t)tcur * DH] = hv;

        xa = na; xb = nb; xc = nc; xd = nd;
        tt = dir ? tt - 1 : tt + 1;
    }
}

// ---------------- Kernel 2: flash-style self-attention ----------------
// grid: BATCH*16 WGs, one per (b, 32-row block). block: 256 threads.
// Per 64-key chunk: stage kv once (row-major, used by both QK^T and PV),
// scores in registers, online softmax (m,l replicated per 16-lane row-group),
// P through small LDS block. LDS total ~34.8 KB -> 4 WG/CU.
#define RB 32      // query rows per block
#define CK 64      // keys per chunk
#define PS 68      // padded row stride (floats); 68%32=4 -> <=2-way conflicts

__global__ __launch_bounds__(256, 4) void attn_kernel(
    const float* __restrict__ h, float* __restrict__ attg)
{
    const int b   = blockIdx.x >> 4;
    const int rb  = blockIdx.x & 15;
    const int tid = threadIdx.x;
    const int row0 = rb * RB;
    const int rgrp = tid >> 4;          // 0..15 : row pair
    const int sgrp = tid & 15;          // 0..15 : key group / d group
    const int r0 = 2 * rgrp, r1 = r0 + 1;

    __shared__ __align__(16) float qL[RB][PS];   // 8.7 KB
    __shared__ __align__(16) float kv[CK][PS];   // 17.4 KB
    __shared__ __align__(16) float pL[RB][PS];   // 8.7 KB

    const float* hb = h + (size_t)b * SEQ * DH;

    for (int i = tid; i < RB * 16; i += 256) {
        const int r = i >> 4, dq = i & 15;
        *(float4*)&qL[r][dq * 4] = *(const float4*)&hb[(row0 + r) * DH + dq * 4];
    }

    float m0 = -1e30f, m1 = -1e30f, l0 = 0.f, l1 = 0.f;
    float o0[4] = {0.f, 0.f, 0.f, 0.f}, o1[4] = {0.f, 0.f, 0.f, 0.f};
    __syncthreads();

    for (int cc = 0; cc < SEQ / CK; ++cc) {
        // stage keys/values chunk (coalesced: consecutive tid -> consecutive 16B)
        const float* src = hb + (size_t)(cc * CK) * DH;
        for (int i = tid; i < CK * 16; i += 256) {
            const int r = i >> 4, dq = i & 15;
            *(float4*)&kv[r][dq * 4] = *(const float4*)&src[r * DH + dq * 4];
        }
        __syncthreads();

        // QK^T: rows r0,r1 x keys sgrp+16u
        float a0[4] = {0.f, 0.f, 0.f, 0.f}, a1[4] = {0.f, 0.f, 0.f, 0.f};
#pragma unroll 4
        for (int d0 = 0; d0 < 16; ++d0) {
            const float4 q0 = *(const float4*)&qL[r0][d0 * 4];
            const float4 q1 = *(const float4*)&qL[r1][d0 * 4];
#pragma unroll
            for (int u = 0; u < 4; ++u) {
                const float4 k4 = *(const float4*)&kv[sgrp + 16 * u][d0 * 4];
                a0[u] = fmaf(q0.x, k4.x, fmaf(q0.y, k4.y, fmaf(q0.z, k4.z, fmaf(q0.w, k4.w, a0[u]))));
                a1[u] = fmaf(q1.x, k4.x, fmaf(q1.y, k4.y, fmaf(q1.z, k4.z, fmaf(q1.w, k4.w, a1[u]))));
            }
        }

        // online softmax update (reduce over the 16 sgrp lanes of this row group)
        float cm0 = fmaxf(fmaxf(a0[0], a0[1]), fmaxf(a0[2], a0[3]));
        float cm1 = fmaxf(fmaxf(a1[0], a1[1]), fmaxf(a1[2], a1[3]));
#pragma unroll
        for (int msk = 1; msk < 16; msk <<= 1) {
            cm0 = fmaxf(cm0, __shfl_xor(cm0, msk));
            cm1 = fmaxf(cm1, __shfl_xor(cm1, msk));
        }
        const float mn0 = fmaxf(m0, cm0), mn1 = fmaxf(m1, cm1);
        const float sc0 = expf(m0 - mn0), sc1 = expf(m1 - mn1);
        float p0[4], p1[4];
        float ps0 = 0.f, ps1 = 0.f;
#pragma unroll
        for (int u = 0; u < 4; ++u) {
            p0[u] = expf(a0[u] - mn0); ps0 += p0[u];
            p1[u] = expf(a1[u] - mn1); ps1 += p1[u];
        }
#pragma unroll
        for (int msk = 1; msk < 16; msk <<= 1) {
            ps0 += __shfl_xor(ps0, msk);
            ps1 += __shfl_xor(ps1, msk);
        }
        l0 = l0 * sc0 + ps0;  m0 = mn0;
        l1 = l1 * sc1 + ps1;  m1 = mn1;
#pragma unroll
        for (int w = 0; w < 4; ++w) { o0[w] *= sc0; o1[w] *= sc1; }
#pragma unroll
        for (int u = 0; u < 4; ++u) {
            pL[r0][sgrp + 16 * u] = p0[u];
            pL[r1][sgrp + 16 * u] = p1[u];
        }
        __syncthreads();

        // PV: out[r][4*sgrp..+3] += sum_s p[r][s] * kv[s][...]
#pragma unroll 4
        for (int sq = 0; sq < 16; ++sq) {
            const float4 p40 = *(const float4*)&pL[r0][sq * 4];
            const float4 p41 = *(const float4*)&pL[r1][sq * 4];
            const float pu0[4] = {p40.x, p40.y, p40.z, p40.w};
            const float pu1[4] = {p41.x, p41.y, p41.z, p41.w};
#pragma unroll
            for (int u = 0; u < 4; ++u) {
                const float4 v4 = *(const float4*)&kv[sq * 4 + u][sgrp * 4];
                o0[0] = fmaf(pu0[u], v4.x, o0[0]);
                o0[1] = fmaf(pu0[u], v4.y, o0[1]);
                o0[2] = fmaf(pu0[u], v4.z, o0[2]);
                o0[3] = fmaf(pu0[u], v4.w, o0[3]);
                o1[0] = fmaf(pu1[u], v4.x, o1[0]);
                o1[1] = fmaf(pu1[u], v4.y, o1[1]);
                o1[2] = fmaf(pu1[u], v4.z, o1[2]);
                o1[3] = fmaf(pu1[u], v4.w, o1[3]);
            }
        }
        __syncthreads();   // kv & pL fully consumed before next stage
    }

    const float il0 = 1.0f / l0, il1 = 1.0f / l1;
    float* op0 = attg + ((size_t)b * SEQ + row0 + r0) * DH + sgrp * 4;
    *(float4*)op0 = make_float4(o0[0] * il0, o0[1] * il0, o0[2] * il0, o0[3] * il0);
    float* op1 = op0 + DH;
    *(float4*)op1 = make_float4(o1[0] * il1, o1[1] * il1, o1[2] * il1, o1[3] * il1);
}

// ---------------- Kernel 3: pooled + LSTM2 + dense ----------------
__global__ __launch_bounds__(128) void final_kernel(
    const float* __restrict__ hbuf, const float* __restrict__ attg,
    const float* __restrict__ W2, const float* __restrict__ b2,
    const float* __restrict__ Wd1, const float* __restrict__ bd1,
    const float* __restrict__ Wd2, const float* __restrict__ bd2,
    float* __restrict__ out)
{
    const int b = blockIdx.x;
    const int tid = threadIdx.x;
    __shared__ float part[2][DH];
    __shared__ float pooled[DH];
    __shared__ float zsh[G4];
    __shared__ float h2[HID];
    __shared__ float a1[16];

    const float* hb = hbuf + (size_t)b * SEQ * DH;
    const float* ab = attg + (size_t)b * SEQ * DH;
    const int d = tid & 63, half = tid >> 6;
    float acc = 0.f;
    for (int t = half * (SEQ / 2); t < (half + 1) * (SEQ / 2); ++t)
        acc = fmaf(hb[t * DH + d], ab[t * DH + d], acc);
    part[half][d] = acc;
    __syncthreads();
    if (tid < DH) pooled[tid] = part[0][tid] + part[1][tid];
    __syncthreads();

    float z = b2[tid];
    for (int k = 0; k < DH; ++k) z = fmaf(pooled[k], W2[k * G4 + tid], z);
    zsh[tid] = z;
    __syncthreads();
    if (tid < HID) {
        const float zi = zsh[tid], zg = zsh[2 * HID + tid], zo = zsh[3 * HID + tid];
        const float cc = sigf(zi) * tanh_fast(zg);
        h2[tid] = sigf(zo) * tanh_fast(cc);
    }
    __syncthreads();
    if (tid < 16) {
        float a = bd1[tid];
        for (int k = 0; k < HID; ++k) a = fmaf(h2[k], Wd1[k * 16 + tid], a);
        a1[tid] = fmaxf(a, 0.0f);
    }
    __syncthreads();
    if (tid == 0) {
        float y = bd2[0];
        for (int k = 0; k < 16; ++k) y = fmaf(a1[k], Wd2[k], y);
        out[b] = y;
    }
}

extern "C" void kernel_launch(void* const* d_in, const int* in_sizes, int n_in,
                              void* d_out, int out_size, void* d_ws, size_t ws_size,
                              hipStream_t stream)
{
    (void)in_sizes; (void)n_in; (void)out_size; (void)ws_size;
    const float* x   = (const float*)d_in[0];
    const float* Wf  = (const float*)d_in[1];
    const float* Uf  = (const float*)d_in[2];
    const float* bf  = (const float*)d_in[3];
    const float* Wb  = (const float*)d_in[4];
    const float* Ub  = (const float*)d_in[5];
    const float* bb  = (const float*)d_in[6];
    const float* W2  = (const float*)d_in[7];
    // d_in[8] = U2 is mathematically unused (zero initial state in second LSTM)
    const float* b2  = (const float*)d_in[9];
    const float* Wd1 = (const float*)d_in[10];
    const float* bd1 = (const float*)d_in[11];
    const float* Wd2 = (const float*)d_in[12];
    const float* bd2 = (const float*)d_in[13];
    float* out = (float*)d_out;

    float* hbuf = (float*)d_ws;                              // [B,T,64]
    float* attg = hbuf + (size_t)BATCH * SEQ * DH;           // [B,T,64]

    hipLaunchKernelGGL(lstm_kernel, dim3(BATCH * 2), dim3(64), 0, stream,
                       x, Wf, Uf, bf, Wb, Ub, bb, hbuf);
    hipLaunchKernelGGL(attn_kernel, dim3(BATCH * 16), dim3(256), 0, stream,
                       hbuf, attg);
    hipLaunchKernelGGL(final_kernel, dim3(BATCH), dim3(128), 0, stream,
                       hbuf, attg, W2, b2, Wd1, bd1, Wd2, bd2, out);
}

// Round 6
// 447.128 us; speedup vs baseline: 1.8344x; 1.1972x over previous
//
#include <hip/hip_runtime.h>
#include <math.h>

#define BATCH 128
#define SEQ 512
#define DIN 16
#define HID 32
#define G4 128   // 4*HID
#define DH 64    // 2*HID
#define LOG2E 1.44269504f

__device__ __forceinline__ float rcpf(float x) { return __builtin_amdgcn_rcpf(x); }

// sigmoid via v_exp + v_rcp (no IEEE div). ~1ulp.
__device__ __forceinline__ float sigf(float x) {
    return rcpf(1.0f + exp2f(x * -LOG2E));
}
// tanh via v_exp + v_rcp. Saturates correctly at +/-inf.
__device__ __forceinline__ float tanh_fast(float x) {
    return 1.0f - 2.0f * rcpf(1.0f + exp2f(x * (2.0f * LOG2E)));
}
__device__ __forceinline__ float rlane(float v, int lane) {
    return __int_as_float(__builtin_amdgcn_readlane(__float_as_int(v), lane));
}

// ---------------- Kernel 1: BiLSTM scan, single wave per (b,dir) ----------------
// 64 threads; thread t owns gate columns t and t+64.
// Lanes 0..31: (i_j, g_j); lanes 32..63: (f_j, o_j). h on lanes 0..31, broadcast
// via v_readlane; f,o cross via shfl_xor(32).
__global__ __launch_bounds__(64) void lstm_kernel(
    const float* __restrict__ x,
    const float* __restrict__ Wf, const float* __restrict__ Uf, const float* __restrict__ bf,
    const float* __restrict__ Wb, const float* __restrict__ Ub, const float* __restrict__ bb,
    float* __restrict__ hbuf)    // [B, T, 64] (fwd -> [:,:,0:32], bwd -> [:,:,32:64])
{
    const int b = blockIdx.x >> 1;
    const int dir = blockIdx.x & 1;
    const int t0 = threadIdx.x;

    const float* W = dir ? Wb : Wf;
    const float* U = dir ? Ub : Uf;
    const float* bias = dir ? bb : bf;
    const int c0 = t0, c1 = t0 + 64;

    float w0[DIN], w1[DIN];
#pragma unroll
    for (int d = 0; d < DIN; ++d) { w0[d] = W[d * G4 + c0]; w1[d] = W[d * G4 + c1]; }
    float u0[HID], u1[HID];
#pragma unroll
    for (int k = 0; k < HID; ++k) { u0[k] = U[k * G4 + c0]; u1[k] = U[k * G4 + c1]; }
    const float b0 = bias[c0], b1 = bias[c1];

    const bool lo = (t0 < 32);
    // branchless gate-1 parameters (loop-invariant): lo -> tanh, hi -> sigmoid
    const float s1 = lo ? (2.0f * LOG2E) : -LOG2E;
    const float a1 = lo ? -2.0f : 1.0f;
    const float b1c = lo ? 1.0f : 0.0f;

    __shared__ __align__(16) float4 xs4[SEQ * 4];   // 32 KB: whole x[b]
    const float4* xg = (const float4*)(x + (size_t)b * SEQ * DIN);
    for (int i = t0; i < SEQ * 4; i += 64) xs4[i] = xg[i];
    __syncthreads();

    float c = 0.f, hv = 0.f;
    float* outp = hbuf + (size_t)b * SEQ * DH + dir * HID + (t0 & 31);

    int tt = dir ? (SEQ - 1) : 0;
    float4 xa = xs4[tt * 4 + 0], xb = xs4[tt * 4 + 1];
    float4 xc = xs4[tt * 4 + 2], xd = xs4[tt * 4 + 3];

    for (int t = 0; t < SEQ; ++t) {
        const int tcur = tt;
        const int tn1 = t + 1 < SEQ ? t + 1 : SEQ - 1;
        const int tnx = dir ? (SEQ - 1 - tn1) : tn1;
        float4 na = xs4[tnx * 4 + 0], nb = xs4[tnx * 4 + 1];
        float4 nc = xs4[tnx * 4 + 2], nd = xs4[tnx * 4 + 3];

        // 4 independent accumulator chains per column
        float q00 = b0, q01 = 0.f, q02 = 0.f, q03 = 0.f;
        float q10 = b1, q11 = 0.f, q12 = 0.f, q13 = 0.f;

        // x part: d0-7 -> chain0, d8-15 -> chain1
        q00 = fmaf(xa.x, w0[0], q00);  q00 = fmaf(xa.y, w0[1], q00);
        q00 = fmaf(xa.z, w0[2], q00);  q00 = fmaf(xa.w, w0[3], q00);
        q00 = fmaf(xb.x, w0[4], q00);  q00 = fmaf(xb.y, w0[5], q00);
        q00 = fmaf(xb.z, w0[6], q00);  q00 = fmaf(xb.w, w0[7], q00);
        q01 = fmaf(xc.x, w0[8], q01);  q01 = fmaf(xc.y, w0[9], q01);
        q01 = fmaf(xc.z, w0[10], q01); q01 = fmaf(xc.w, w0[11], q01);
        q01 = fmaf(xd.x, w0[12], q01); q01 = fmaf(xd.y, w0[13], q01);
        q01 = fmaf(xd.z, w0[14], q01); q01 = fmaf(xd.w, w0[15], q01);
        q10 = fmaf(xa.x, w1[0], q10);  q10 = fmaf(xa.y, w1[1], q10);
        q10 = fmaf(xa.z, w1[2], q10);  q10 = fmaf(xa.w, w1[3], q10);
        q10 = fmaf(xb.x, w1[4], q10);  q10 = fmaf(xb.y, w1[5], q10);
        q10 = fmaf(xb.z, w1[6], q10);  q10 = fmaf(xb.w, w1[7], q10);
        q11 = fmaf(xc.x, w1[8], q11);  q11 = fmaf(xc.y, w1[9], q11);
        q11 = fmaf(xc.z, w1[10], q11); q11 = fmaf(xc.w, w1[11], q11);
        q11 = fmaf(xd.x, w1[12], q11); q11 = fmaf(xd.y, w1[13], q11);
        q11 = fmaf(xd.z, w1[14], q11); q11 = fmaf(xd.w, w1[15], q11);

        // U part: h broadcast from lanes 0..31; k 0-15 -> chains 2, k 16-31 -> chains 3
#pragma unroll
        for (int k = 0; k < 16; k += 2) {
            const float h0 = rlane(hv, k);
            const float h1 = rlane(hv, k + 1);
            q02 = fmaf(h0, u0[k], q02);
            q12 = fmaf(h0, u1[k], q12);
            q03 = fmaf(h1, u0[k + 1], q03);
            q13 = fmaf(h1, u1[k + 1], q13);
        }
#pragma unroll
        for (int k = 16; k < 32; k += 2) {
            const float h0 = rlane(hv, k);
            const float h1 = rlane(hv, k + 1);
            q00 = fmaf(h0, u0[k], q00);
            q10 = fmaf(h0, u1[k], q10);
            q01 = fmaf(h1, u0[k + 1], q01);
            q11 = fmaf(h1, u1[k + 1], q11);
        }
        const float z0 = (q00 + q01) + (q02 + q03);
        const float z1 = (q10 + q11) + (q12 + q13);

        // gates (no divisions, no divergent branch)
        const float g0 = rcpf(1.0f + exp2f(z0 * -LOG2E));        // si | sf
        const float e1 = exp2f(z1 * s1);
        const float g1 = fmaf(a1, rcpf(1.0f + e1), b1c);         // tg | so
        const float fo0 = __shfl_xor(g0, 32);                    // sf (low lanes)
        const float fo1 = __shfl_xor(g1, 32);                    // so (low lanes)
        c = fmaf(fo0, c, g0 * g1);                               // c = sf*c + si*tg
        hv = fo1 * tanh_fast(c);                                 // h = so*tanh(c)
        if (lo) outp[(size_t)tcur * DH] = hv;

        xa = na; xb = nb; xc = nc; xd = nd;
        tt = dir ? tt - 1 : tt + 1;
    }
}

// ---------------- Kernel 2: flash-style self-attention (log2-domain softmax) ----
#define RB 32      // query rows per block
#define CK 64      // keys per chunk
#define PS 68      // padded row stride

__global__ __launch_bounds__(256, 4) void attn_kernel(
    const float* __restrict__ h, float* __restrict__ attg)
{
    const int b   = blockIdx.x >> 4;
    const int rb  = blockIdx.x & 15;
    const int tid = threadIdx.x;
    const int row0 = rb * RB;
    const int rgrp = tid >> 4;
    const int sgrp = tid & 15;
    const int r0 = 2 * rgrp, r1 = r0 + 1;

    __shared__ __align__(16) float qL[RB][PS];
    __shared__ __align__(16) float kv[CK][PS];
    __shared__ __align__(16) float pL[RB][PS];

    const float* hb = h + (size_t)b * SEQ * DH;

    for (int i = tid; i < RB * 16; i += 256) {
        const int r = i >> 4, dq = i & 15;
        *(float4*)&qL[r][dq * 4] = *(const float4*)&hb[(row0 + r) * DH + dq * 4];
    }

    float m0 = -1e30f, m1 = -1e30f, l0 = 0.f, l1 = 0.f;
    float o0[4] = {0.f, 0.f, 0.f, 0.f}, o1[4] = {0.f, 0.f, 0.f, 0.f};
    __syncthreads();

    for (int cc = 0; cc < SEQ / CK; ++cc) {
        const float* src = hb + (size_t)(cc * CK) * DH;
        for (int i = tid; i < CK * 16; i += 256) {
            const int r = i >> 4, dq = i & 15;
            *(float4*)&kv[r][dq * 4] = *(const float4*)&src[r * DH + dq * 4];
        }
        __syncthreads();

        // QK^T
        float a0[4] = {0.f, 0.f, 0.f, 0.f}, a1[4] = {0.f, 0.f, 0.f, 0.f};
#pragma unroll 4
        for (int d0 = 0; d0 < 16; ++d0) {
            const float4 q0 = *(const float4*)&qL[r0][d0 * 4];
            const float4 q1 = *(const float4*)&qL[r1][d0 * 4];
#pragma unroll
            for (int u = 0; u < 4; ++u) {
                const float4 k4 = *(const float4*)&kv[sgrp + 16 * u][d0 * 4];
                a0[u] = fmaf(q0.x, k4.x, fmaf(q0.y, k4.y, fmaf(q0.z, k4.z, fmaf(q0.w, k4.w, a0[u]))));
                a1[u] = fmaf(q1.x, k4.x, fmaf(q1.y, k4.y, fmaf(q1.z, k4.z, fmaf(q1.w, k4.w, a1[u]))));
            }
        }
        // move scores to log2 domain once; everything downstream uses exp2
#pragma unroll
        for (int u = 0; u < 4; ++u) { a0[u] *= LOG2E; a1[u] *= LOG2E; }

        // online softmax in log2 domain
        float cm0 = fmaxf(fmaxf(a0[0], a0[1]), fmaxf(a0[2], a0[3]));
        float cm1 = fmaxf(fmaxf(a1[0], a1[1]), fmaxf(a1[2], a1[3]));
#pragma unroll
        for (int msk = 1; msk < 16; msk <<= 1) {
            cm0 = fmaxf(cm0, __shfl_xor(cm0, msk));
            cm1 = fmaxf(cm1, __shfl_xor(cm1, msk));
        }
        const float mn0 = fmaxf(m0, cm0), mn1 = fmaxf(m1, cm1);
        const float sc0 = exp2f(m0 - mn0), sc1 = exp2f(m1 - mn1);
        float p0[4], p1[4];
        float ps0 = 0.f, ps1 = 0.f;
#pragma unroll
        for (int u = 0; u < 4; ++u) {
            p0[u] = exp2f(a0[u] - mn0); ps0 += p0[u];
            p1[u] = exp2f(a1[u] - mn1); ps1 += p1[u];
        }
#pragma unroll
        for (int msk = 1; msk < 16; msk <<= 1) {
            ps0 += __shfl_xor(ps0, msk);
            ps1 += __shfl_xor(ps1, msk);
        }
        l0 = l0 * sc0 + ps0;  m0 = mn0;
        l1 = l1 * sc1 + ps1;  m1 = mn1;
#pragma unroll
        for (int w = 0; w < 4; ++w) { o0[w] *= sc0; o1[w] *= sc1; }
#pragma unroll
        for (int u = 0; u < 4; ++u) {
            pL[r0][sgrp + 16 * u] = p0[u];
            pL[r1][sgrp + 16 * u] = p1[u];
        }
        __syncthreads();

        // PV
#pragma unroll 4
        for (int sq = 0; sq < 16; ++sq) {
            const float4 p40 = *(const float4*)&pL[r0][sq * 4];
            const float4 p41 = *(const float4*)&pL[r1][sq * 4];
            const float pu0[4] = {p40.x, p40.y, p40.z, p40.w};
            const float pu1[4] = {p41.x, p41.y, p41.z, p41.w};
#pragma unroll
            for (int u = 0; u < 4; ++u) {
                const float4 v4 = *(const float4*)&kv[sq * 4 + u][sgrp * 4];
                o0[0] = fmaf(pu0[u], v4.x, o0[0]);
                o0[1] = fmaf(pu0[u], v4.y, o0[1]);
                o0[2] = fmaf(pu0[u], v4.z, o0[2]);
                o0[3] = fmaf(pu0[u], v4.w, o0[3]);
                o1[0] = fmaf(pu1[u], v4.x, o1[0]);
                o1[1] = fmaf(pu1[u], v4.y, o1[1]);
                o1[2] = fmaf(pu1[u], v4.z, o1[2]);
                o1[3] = fmaf(pu1[u], v4.w, o1[3]);
            }
        }
        __syncthreads();
    }

    const float il0 = 1.0f / l0, il1 = 1.0f / l1;
    float* op0 = attg + ((size_t)b * SEQ + row0 + r0) * DH + sgrp * 4;
    *(float4*)op0 = make_float4(o0[0] * il0, o0[1] * il0, o0[2] * il0, o0[3] * il0);
    float* op1 = op0 + DH;
    *(float4*)op1 = make_float4(o1[0] * il1, o1[1] * il1, o1[2] * il1, o1[3] * il1);
}

// ---------------- Kernel 3: pooled + LSTM2 + dense ----------------
__global__ __launch_bounds__(128) void final_kernel(
    const float* __restrict__ hbuf, const float* __restrict__ attg,
    const float* __restrict__ W2, const float* __restrict__ b2,
    const float* __restrict__ Wd1, const float* __restrict__ bd1,
    const float* __restrict__ Wd2, const float* __restrict__ bd2,
    float* __restrict__ out)
{
    const int b = blockIdx.x;
    const int tid = threadIdx.x;
    __shared__ float part[2][DH];
    __shared__ float pooled[DH];
    __shared__ float zsh[G4];
    __shared__ float h2[HID];
    __shared__ float a1[16];

    const float* hb = hbuf + (size_t)b * SEQ * DH;
    const float* ab = attg + (size_t)b * SEQ * DH;
    const int d = tid & 63, half = tid >> 6;
    float acc = 0.f;
    for (int t = half * (SEQ / 2); t < (half + 1) * (SEQ / 2); ++t)
        acc = fmaf(hb[t * DH + d], ab[t * DH + d], acc);
    part[half][d] = acc;
    __syncthreads();
    if (tid < DH) pooled[tid] = part[0][tid] + part[1][tid];
    __syncthreads();

    float z = b2[tid];
    for (int k = 0; k < DH; ++k) z = fmaf(pooled[k], W2[k * G4 + tid], z);
    zsh[tid] = z;
    __syncthreads();
    if (tid < HID) {
        const float zi = zsh[tid], zg = zsh[2 * HID + tid], zo = zsh[3 * HID + tid];
        const float cc = sigf(zi) * tanh_fast(zg);
        h2[tid] = sigf(zo) * tanh_fast(cc);
    }
    __syncthreads();
    if (tid < 16) {
        float a = bd1[tid];
        for (int k = 0; k < HID; ++k) a = fmaf(h2[k], Wd1[k * 16 + tid], a);
        a1[tid] = fmaxf(a, 0.0f);
    }
    __syncthreads();
    if (tid == 0) {
        float y = bd2[0];
        for (int k = 0; k < 16; ++k) y = fmaf(a1[k], Wd2[k], y);
        out[b] = y;
    }
}

extern "C" void kernel_launch(void* const* d_in, const int* in_sizes, int n_in,
                              void* d_out, int out_size, void* d_ws, size_t ws_size,
                              hipStream_t stream)
{
    (void)in_sizes; (void)n_in; (void)out_size; (void)ws_size;
    const float* x   = (const float*)d_in[0];
    const float* Wf  = (const float*)d_in[1];
    const float* Uf  = (const float*)d_in[2];
    const float* bf  = (const float*)d_in[3];
    const float* Wb  = (const float*)d_in[4];
    const float* Ub  = (const float*)d_in[5];
    const float* bb  = (const float*)d_in[6];
    const float* W2  = (const float*)d_in[7];
    // d_in[8] = U2 unused (zero initial state in second LSTM)
    const float* b2  = (const float*)d_in[9];
    const float* Wd1 = (const float*)d_in[10];
    const float* bd1 = (const float*)d_in[11];
    const float* Wd2 = (const float*)d_in[12];
    const float* bd2 = (const float*)d_in[13];
    float* out = (float*)d_out;

    float* hbuf = (float*)d_ws;                              // [B,T,64]
    float* attg = hbuf + (size_t)BATCH * SEQ * DH;           // [B,T,64]

    hipLaunchKernelGGL(lstm_kernel, dim3(BATCH * 2), dim3(64), 0, stream,
                       x, Wf, Uf, bf, Wb, Ub, bb, hbuf);
    hipLaunchKernelGGL(attn_kernel, dim3(BATCH * 16), dim3(256), 0, stream,
                       hbuf, attg);
    hipLaunchKernelGGL(final_kernel, dim3(BATCH), dim3(128), 0, stream,
                       hbuf, attg, W2, b2, Wd1, bd1, Wd2, bd2, out);
}